// Round 18
// baseline (133.016 us; speedup 1.0000x reference)
//
#include <hip/hip_runtime.h>
#include <hip/hip_bf16.h>

#define DIM 128
#define EPB 4096          // edges per partition chunk (1024 thr x 4)
#define SRC_BITS 17       // n_nodes < 131072
#define SRC_MASK 0x1FFFF
#define TMAX 8
#define CAP 4864          // per-bucket slot capacity (mean 4092 + 12 sigma)

typedef short short8 __attribute__((ext_vector_type(8)));
typedef float f32x4 __attribute__((ext_vector_type(4)));

static __device__ __forceinline__ unsigned short f2bf(float f) {
    unsigned u = __builtin_bit_cast(unsigned, f);
    unsigned r = (u + 0x7fffu + ((u >> 16) & 1u)) >> 16;  // RNE
    return (unsigned short)r;
}

// -------------------- GEMM: S2 = bf16(X @ W) via MFMA --------------------
// Block 0 additionally zeroes the 512 line-padded bucket cursors.
__global__ __launch_bounds__(256) void gemm_xw_mfma(const float* __restrict__ X,
                                                    const float* __restrict__ W,
                                                    unsigned short* __restrict__ S2,
                                                    int* __restrict__ cursor,
                                                    int n_nodes) {
    __shared__ unsigned short wlds[DIM * DIM];  // 32 KB, swizzled W^T bf16

    if (blockIdx.x == 0) {
        for (int i = threadIdx.x; i < 512; i += 256) cursor[i * 16] = 0;
    }

    for (int idx = threadIdx.x; idx < DIM * DIM; idx += 256) {
        const int k = idx >> 7;
        const int n = idx & 127;
        wlds[n * DIM + (k ^ ((n & 7) << 3))] = f2bf(W[idx]);
    }
    __syncthreads();

    const int wave = threadIdx.x >> 6;
    const int lane = threadIdx.x & 63;
    const int row_base = blockIdx.x * 64 + wave * 16;
    const int mrow = lane & 15;
    const int kq = lane >> 4;
    const int kq8 = kq * 8;

    int rr = row_base + mrow;
    if (rr >= n_nodes) rr = n_nodes - 1;
    const float4* Xr = (const float4*)(X + (size_t)rr * DIM);

    short8 a[4];
#pragma unroll
    for (int s = 0; s < 4; ++s) {
        const float4 v0 = Xr[s * 8 + kq * 2];
        const float4 v1 = Xr[s * 8 + kq * 2 + 1];
        short8 av;
        av[0] = f2bf(v0.x); av[1] = f2bf(v0.y); av[2] = f2bf(v0.z); av[3] = f2bf(v0.w);
        av[4] = f2bf(v1.x); av[5] = f2bf(v1.y); av[6] = f2bf(v1.z); av[7] = f2bf(v1.w);
        a[s] = av;
    }

    f32x4 acc[8];
#pragma unroll
    for (int c = 0; c < 8; ++c) acc[c] = (f32x4){0.f, 0.f, 0.f, 0.f};

    const int swz = (lane & 7) << 3;
#pragma unroll
    for (int s = 0; s < 4; ++s) {
        const int k0 = s * 32 + kq8;
#pragma unroll
        for (int c = 0; c < 8; ++c) {
            const int n = c * 16 + mrow;
            const short8 bv = *(const short8*)(&wlds[n * DIM + (k0 ^ swz)]);
            acc[c] = __builtin_amdgcn_mfma_f32_16x16x32_bf16(a[s], bv, acc[c], 0, 0, 0);
        }
    }

#pragma unroll
    for (int reg = 0; reg < 4; ++reg) {
        const int g_r = row_base + kq * 4 + reg;
        if (g_r < n_nodes) {
            unsigned short* orow = S2 + (size_t)g_r * DIM + mrow;
#pragma unroll
            for (int c = 0; c < 8; ++c) orow[c * 16] = f2bf(acc[c][reg]);
        }
    }
}

// ---------- partB: bump-alloc scatter into per-bucket slots (bucket = dst>>8) ------
// Stream-once inputs (dst/src/ew) use nontemporal loads to preserve L2/L3
// residency of S2. Reservation: ONE returning global atomic per (block,bucket).
__global__ __launch_bounds__(1024) void partB_scatter(const int* __restrict__ dst,
                                                      const int* __restrict__ src,
                                                      const float* __restrict__ ew,
                                                      int* __restrict__ cursor,
                                                      int2* __restrict__ part_sw,
                                                      int n_edges, int nbkt) {
    __shared__ int lc[512];
    __shared__ int lbase[512];
    const int blk = blockIdx.x;
    for (int i = threadIdx.x; i < 512; i += 1024) lc[i] = 0;
    __syncthreads();

    const int base = blk * EPB;
    int d[4], rk[4];
#pragma unroll
    for (int u = 0; u < 4; ++u) {
        const int e = base + u * 1024 + threadIdx.x;
        if (e < n_edges) {
            d[u] = __builtin_nontemporal_load(dst + e);
            rk[u] = atomicAdd(&lc[d[u] >> 8], 1);
        }
    }
    __syncthreads();

    for (int b = threadIdx.x; b < nbkt; b += 1024)
        lbase[b] = (lc[b] > 0) ? atomicAdd(&cursor[b * 16], lc[b]) : 0;
    __syncthreads();

#pragma unroll
    for (int u = 0; u < 4; ++u) {
        const int e = base + u * 1024 + threadIdx.x;
        if (e < n_edges) {
            const int s = __builtin_nontemporal_load(src + e);
            const float w = __builtin_nontemporal_load(ew + e);
            const int bin = d[u] >> 8;
            const int pos = bin * CAP + lbase[bin] + rk[u];
            part_sw[pos] = make_int2(s | ((d[u] & 255) << SRC_BITS),
                                     __float_as_int(w));
        }
    }
}

// ---------- partC: per-bucket CSR finish in slotted layout ----------
__global__ __launch_bounds__(1024) void partC_csr(const int2* __restrict__ part_sw,
                                                  const int* __restrict__ cursor,
                                                  int2* __restrict__ offs2,
                                                  int2* __restrict__ edge_sw,
                                                  int n_nodes) {
    __shared__ int lcnt[256];
    __shared__ int loff[256];
    const int b = blockIdx.x;
    const int bstart = b * CAP;
    const int bcount = cursor[b * 16];

    if (threadIdx.x < 256) lcnt[threadIdx.x] = 0;
    __syncthreads();

    int2 sw_r[TMAX];
    int rk_r[TMAX];
    const int ntile = (bcount + 1023) >> 10;
#pragma unroll
    for (int t = 0; t < TMAX; ++t) {
        if (t < ntile) {
            const int i = t * 1024 + threadIdx.x;
            if (i < bcount) {
                const long long raw = __builtin_nontemporal_load(
                    (const long long*)(part_sw + bstart + i));
                const int2 v = make_int2((int)(unsigned)(raw & 0xffffffffLL),
                                         (int)(raw >> 32));
                sw_r[t] = v;
                rk_r[t] = atomicAdd(&lcnt[(v.x >> SRC_BITS) & 255], 1);
            }
        }
    }
    __syncthreads();

    if (threadIdx.x < 256) loff[threadIdx.x] = lcnt[threadIdx.x];
    __syncthreads();
#pragma unroll
    for (int off = 1; off < 256; off <<= 1) {
        int t_ = 0;
        if (threadIdx.x < 256 && threadIdx.x >= off) t_ = loff[threadIdx.x - off];
        __syncthreads();
        if (threadIdx.x < 256) loff[threadIdx.x] += t_;
        __syncthreads();
    }
    int ex = 0;
    if (threadIdx.x < 256 && threadIdx.x > 0) ex = loff[threadIdx.x - 1];
    __syncthreads();
    if (threadIdx.x < 256) loff[threadIdx.x] = ex;
    __syncthreads();

    const int nb0 = b << 8;
    if (threadIdx.x < 256 && nb0 + threadIdx.x < n_nodes) {
        const int s = bstart + loff[threadIdx.x];
        offs2[nb0 + threadIdx.x] = make_int2(s, s + lcnt[threadIdx.x]);
    }

#pragma unroll
    for (int t = 0; t < TMAX; ++t) {
        if (t < ntile) {
            const int i = t * 1024 + threadIdx.x;
            if (i < bcount) {
                const int ld = (sw_r[t].x >> SRC_BITS) & 255;
                edge_sw[bstart + loff[ld] + rk_r[t]] =
                    make_int2(sw_r[t].x & SRC_MASK, sw_r[t].y);
            }
        }
    }
}

// -------------------- reduce: out[n] = bias + sum ew*S[src] --------------------
// Quarter-wave gather; edge_sw meta via nontemporal load, out via nontemporal
// store — keeps S2 resident in L2/L3.
#define QEXPAND(GV, WW)                                                   \
    acc[0] = fmaf(WW, __int_as_float((GV).x << 16), acc[0]);              \
    acc[1] = fmaf(WW, __int_as_float((GV).x & 0xffff0000u), acc[1]);      \
    acc[2] = fmaf(WW, __int_as_float((GV).y << 16), acc[2]);              \
    acc[3] = fmaf(WW, __int_as_float((GV).y & 0xffff0000u), acc[3]);      \
    acc[4] = fmaf(WW, __int_as_float((GV).z << 16), acc[4]);              \
    acc[5] = fmaf(WW, __int_as_float((GV).z & 0xffff0000u), acc[5]);      \
    acc[6] = fmaf(WW, __int_as_float((GV).w << 16), acc[6]);              \
    acc[7] = fmaf(WW, __int_as_float((GV).w & 0xffff0000u), acc[7]);

__global__ __launch_bounds__(256) void gcn_reduce(const uint4* __restrict__ S2q,
                                                  const int2* __restrict__ edge_sw,
                                                  const int2* __restrict__ offs2,
                                                  const float* __restrict__ bias,
                                                  float* __restrict__ out,
                                                  int n_nodes) {
    const int node = blockIdx.x * 4 + (threadIdx.x >> 6);
    if (node >= n_nodes) return;
    const int lane = threadIdx.x & 63;
    const int grp = lane >> 4;    // edge slot within a 4-edge group
    const int ql = lane & 15;     // 16B chunk of the 256B row

    const int2 se = offs2[node];
    const int start = se.x;
    const int end = se.y;

    float acc[8];
#pragma unroll
    for (int j = 0; j < 8; ++j) acc[j] = 0.f;

    for (int base = start; base < end; base += 64) {
        const int cnt = min(64, end - base);
        int mx = 0, my = 0;           // pad lanes: src=0 (valid row), w=0
        if (lane < cnt) {
            const long long raw = __builtin_nontemporal_load(
                (const long long*)(edge_sw + base + lane));
            mx = (int)(unsigned)(raw & 0xffffffffLL);
            my = (int)(raw >> 32);
        }

        int i = 0;
        for (; i + 16 <= cnt; i += 16) {
            uint4 gv[4];
            float ws[4];
#pragma unroll
            for (int u = 0; u < 4; ++u) {
                const int idx = i + u * 4 + grp;
                const int s = __shfl(mx, idx, 64);
                ws[u] = __int_as_float(__shfl(my, idx, 64));
                gv[u] = S2q[(size_t)s * 16 + ql];
            }
            QEXPAND(gv[0], ws[0]);
            QEXPAND(gv[1], ws[1]);
            QEXPAND(gv[2], ws[2]);
            QEXPAND(gv[3], ws[3]);
        }
        for (; i < cnt; i += 4) {
            const int idx = i + grp;  // idx <= 63; pad slots have w=0
            const int s = __shfl(mx, idx, 64);
            const float w = __int_as_float(__shfl(my, idx, 64));
            const uint4 gv = S2q[(size_t)s * 16 + ql];
            QEXPAND(gv, w);
        }
    }

#pragma unroll
    for (int j = 0; j < 8; ++j) {
        acc[j] += __shfl_xor(acc[j], 16, 64);
        acc[j] += __shfl_xor(acc[j], 32, 64);
    }

    if (lane < 16) {
        const float4 b0 = ((const float4*)bias)[ql * 2];
        const float4 b1 = ((const float4*)bias)[ql * 2 + 1];
        f32x4 o0 = {acc[0] + b0.x, acc[1] + b0.y, acc[2] + b0.z, acc[3] + b0.w};
        f32x4 o1 = {acc[4] + b1.x, acc[5] + b1.y, acc[6] + b1.z, acc[7] + b1.w};
        f32x4* orow = (f32x4*)(out + (size_t)node * DIM) + ql * 2;
        __builtin_nontemporal_store(o0, orow);
        __builtin_nontemporal_store(o1, orow + 1);
    }
}

extern "C" void kernel_launch(void* const* d_in, const int* in_sizes, int n_in,
                              void* d_out, int out_size, void* d_ws, size_t ws_size,
                              hipStream_t stream) {
    const float* X    = (const float*)d_in[0];
    const float* W    = (const float*)d_in[1];
    const float* bias = (const float*)d_in[2];
    const float* ew   = (const float*)d_in[3];
    const int*   src  = (const int*)d_in[4];
    const int*   dst  = (const int*)d_in[5];
    float* out = (float*)d_out;

    const int n_nodes = in_sizes[0] / DIM;
    const int n_edges = in_sizes[3];

    const int nbkt = (n_nodes + 255) >> 8;                 // 391
    const int nchunks = (n_edges + EPB - 1) / EPB;         // 391

    // Workspace layout (bytes):
    char* ws = (char*)d_ws;
    unsigned short* S2 = (unsigned short*)ws;                         // 25.6 MB
    char* p = ws + (size_t)n_nodes * DIM * 2;
    int* cursor = (int*)p;          p += 512 * 16 * 4;                // 32 KB (padded)
    int2* offs2 = (int2*)p;         p += (size_t)n_nodes * 8;         // 800 KB
    int2* part_sw = (int2*)p;       p += (size_t)nbkt * CAP * 8;      // 15.2 MB
    int2* edge_sw = (int2*)p;                                         // 15.2 MB

    // 1. GEMM (bf16 MFMA) + cursor zeroing
    gemm_xw_mfma<<<(n_nodes + 63) / 64, 256, 0, stream>>>(X, W, S2, cursor, n_nodes);

    // 2. Bump-alloc bucket scatter (per-edge atomics LDS-scope;
    //    391 reservation atomics per block)
    partB_scatter<<<nchunks, 1024, 0, stream>>>(dst, src, ew, cursor, part_sw,
                                                n_edges, nbkt);

    // 3. Per-bucket CSR finish in slotted layout
    partC_csr<<<nbkt, 1024, 0, stream>>>(part_sw, cursor, offs2, edge_sw, n_nodes);

    // 4. Per-node reduction (bias fused, single non-atomic write)
    gcn_reduce<<<(n_nodes + 3) / 4, 256, 0, stream>>>((const uint4*)S2,
                                                      edge_sw, offs2,
                                                      bias, out, n_nodes);
}

// Round 19
// 124.178 us; speedup vs baseline: 1.0712x; 1.0712x over previous
//
#include <hip/hip_runtime.h>
#include <hip/hip_bf16.h>

#define DIM 128
#define EPB 4096          // edges per partition chunk (1024 thr x 4)
#define SRC_BITS 17       // n_nodes < 131072
#define SRC_MASK 0x1FFFF
#define TMAX 8
#define CAP 4864          // per-bucket slot capacity (mean 4092 + 12 sigma)

typedef short short8 __attribute__((ext_vector_type(8)));
typedef float f32x4 __attribute__((ext_vector_type(4)));

static __device__ __forceinline__ unsigned short f2bf(float f) {
    unsigned u = __builtin_bit_cast(unsigned, f);
    unsigned r = (u + 0x7fffu + ((u >> 16) & 1u)) >> 16;  // RNE
    return (unsigned short)r;
}

// -------------------- GEMM: S2 = bf16(X @ W) via MFMA --------------------
// Block 0 additionally zeroes the 512 line-padded bucket cursors.
__global__ __launch_bounds__(256) void gemm_xw_mfma(const float* __restrict__ X,
                                                    const float* __restrict__ W,
                                                    unsigned short* __restrict__ S2,
                                                    int* __restrict__ cursor,
                                                    int n_nodes) {
    __shared__ unsigned short wlds[DIM * DIM];  // 32 KB, swizzled W^T bf16

    if (blockIdx.x == 0) {
        for (int i = threadIdx.x; i < 512; i += 256) cursor[i * 16] = 0;
    }

    for (int idx = threadIdx.x; idx < DIM * DIM; idx += 256) {
        const int k = idx >> 7;
        const int n = idx & 127;
        wlds[n * DIM + (k ^ ((n & 7) << 3))] = f2bf(W[idx]);
    }
    __syncthreads();

    const int wave = threadIdx.x >> 6;
    const int lane = threadIdx.x & 63;
    const int row_base = blockIdx.x * 64 + wave * 16;
    const int mrow = lane & 15;
    const int kq = lane >> 4;
    const int kq8 = kq * 8;

    int rr = row_base + mrow;
    if (rr >= n_nodes) rr = n_nodes - 1;
    const float4* Xr = (const float4*)(X + (size_t)rr * DIM);

    short8 a[4];
#pragma unroll
    for (int s = 0; s < 4; ++s) {
        const float4 v0 = Xr[s * 8 + kq * 2];
        const float4 v1 = Xr[s * 8 + kq * 2 + 1];
        short8 av;
        av[0] = f2bf(v0.x); av[1] = f2bf(v0.y); av[2] = f2bf(v0.z); av[3] = f2bf(v0.w);
        av[4] = f2bf(v1.x); av[5] = f2bf(v1.y); av[6] = f2bf(v1.z); av[7] = f2bf(v1.w);
        a[s] = av;
    }

    f32x4 acc[8];
#pragma unroll
    for (int c = 0; c < 8; ++c) acc[c] = (f32x4){0.f, 0.f, 0.f, 0.f};

    const int swz = (lane & 7) << 3;
#pragma unroll
    for (int s = 0; s < 4; ++s) {
        const int k0 = s * 32 + kq8;
#pragma unroll
        for (int c = 0; c < 8; ++c) {
            const int n = c * 16 + mrow;
            const short8 bv = *(const short8*)(&wlds[n * DIM + (k0 ^ swz)]);
            acc[c] = __builtin_amdgcn_mfma_f32_16x16x32_bf16(a[s], bv, acc[c], 0, 0, 0);
        }
    }

#pragma unroll
    for (int reg = 0; reg < 4; ++reg) {
        const int g_r = row_base + kq * 4 + reg;
        if (g_r < n_nodes) {
            unsigned short* orow = S2 + (size_t)g_r * DIM + mrow;
#pragma unroll
            for (int c = 0; c < 8; ++c) orow[c * 16] = f2bf(acc[c][reg]);
        }
    }
}

// ---------- partB: bump-alloc scatter into per-bucket slots (bucket = dst>>8) ------
// Pass 1: LDS histogram + per-edge local rank. Reservation: ONE returning
// global atomic per (block,bucket) on line-padded cursors. Pass 2: scatter.
__global__ __launch_bounds__(1024) void partB_scatter(const int* __restrict__ dst,
                                                      const int* __restrict__ src,
                                                      const float* __restrict__ ew,
                                                      int* __restrict__ cursor,
                                                      int2* __restrict__ part_sw,
                                                      int n_edges, int nbkt) {
    __shared__ int lc[512];
    __shared__ int lbase[512];
    const int blk = blockIdx.x;
    for (int i = threadIdx.x; i < 512; i += 1024) lc[i] = 0;
    __syncthreads();

    const int base = blk * EPB;
    int d[4], rk[4];
#pragma unroll
    for (int u = 0; u < 4; ++u) {
        const int e = base + u * 1024 + threadIdx.x;
        if (e < n_edges) {
            d[u] = dst[e];
            rk[u] = atomicAdd(&lc[d[u] >> 8], 1);
        }
    }
    __syncthreads();

    for (int b = threadIdx.x; b < nbkt; b += 1024)
        lbase[b] = (lc[b] > 0) ? atomicAdd(&cursor[b * 16], lc[b]) : 0;
    __syncthreads();

#pragma unroll
    for (int u = 0; u < 4; ++u) {
        const int e = base + u * 1024 + threadIdx.x;
        if (e < n_edges) {
            const int bin = d[u] >> 8;
            const int pos = bin * CAP + lbase[bin] + rk[u];
            part_sw[pos] = make_int2(src[e] | ((d[u] & 255) << SRC_BITS),
                                     __float_as_int(ew[e]));
        }
    }
}

// ---------- partC: per-bucket CSR finish in slotted layout ----------
// Sorts the bucket's records by node; writes int2{start,end} offsets.
__global__ __launch_bounds__(1024) void partC_csr(const int2* __restrict__ part_sw,
                                                  const int* __restrict__ cursor,
                                                  int2* __restrict__ offs2,
                                                  int2* __restrict__ edge_sw,
                                                  int n_nodes) {
    __shared__ int lcnt[256];
    __shared__ int loff[256];
    const int b = blockIdx.x;
    const int bstart = b * CAP;
    const int bcount = cursor[b * 16];

    if (threadIdx.x < 256) lcnt[threadIdx.x] = 0;
    __syncthreads();

    int2 sw_r[TMAX];
    int rk_r[TMAX];
    const int ntile = (bcount + 1023) >> 10;
#pragma unroll
    for (int t = 0; t < TMAX; ++t) {
        if (t < ntile) {
            const int i = t * 1024 + threadIdx.x;
            if (i < bcount) {
                const int2 v = part_sw[bstart + i];
                sw_r[t] = v;
                rk_r[t] = atomicAdd(&lcnt[(v.x >> SRC_BITS) & 255], 1);
            }
        }
    }
    __syncthreads();

    if (threadIdx.x < 256) loff[threadIdx.x] = lcnt[threadIdx.x];
    __syncthreads();
#pragma unroll
    for (int off = 1; off < 256; off <<= 1) {
        int t_ = 0;
        if (threadIdx.x < 256 && threadIdx.x >= off) t_ = loff[threadIdx.x - off];
        __syncthreads();
        if (threadIdx.x < 256) loff[threadIdx.x] += t_;
        __syncthreads();
    }
    int ex = 0;
    if (threadIdx.x < 256 && threadIdx.x > 0) ex = loff[threadIdx.x - 1];
    __syncthreads();
    if (threadIdx.x < 256) loff[threadIdx.x] = ex;
    __syncthreads();

    const int nb0 = b << 8;
    if (threadIdx.x < 256 && nb0 + threadIdx.x < n_nodes) {
        const int s = bstart + loff[threadIdx.x];
        offs2[nb0 + threadIdx.x] = make_int2(s, s + lcnt[threadIdx.x]);
    }

#pragma unroll
    for (int t = 0; t < TMAX; ++t) {
        if (t < ntile) {
            const int i = t * 1024 + threadIdx.x;
            if (i < bcount) {
                const int ld = (sw_r[t].x >> SRC_BITS) & 255;
                edge_sw[bstart + loff[ld] + rk_r[t]] =
                    make_int2(sw_r[t].x & SRC_MASK, sw_r[t].y);
            }
        }
    }
}

// -------------------- reduce: out[n] = bias + sum ew*S[src] --------------------
// Quarter-wave gather: lane-group g = lane>>4 handles edge i+g; one uint4
// per lane covers the 256B S2 row with 16 lanes -> 4 edges per instruction.
#define QEXPAND(GV, WW)                                                   \
    acc[0] = fmaf(WW, __int_as_float((GV).x << 16), acc[0]);              \
    acc[1] = fmaf(WW, __int_as_float((GV).x & 0xffff0000u), acc[1]);      \
    acc[2] = fmaf(WW, __int_as_float((GV).y << 16), acc[2]);              \
    acc[3] = fmaf(WW, __int_as_float((GV).y & 0xffff0000u), acc[3]);      \
    acc[4] = fmaf(WW, __int_as_float((GV).z << 16), acc[4]);              \
    acc[5] = fmaf(WW, __int_as_float((GV).z & 0xffff0000u), acc[5]);      \
    acc[6] = fmaf(WW, __int_as_float((GV).w << 16), acc[6]);              \
    acc[7] = fmaf(WW, __int_as_float((GV).w & 0xffff0000u), acc[7]);

__global__ __launch_bounds__(256) void gcn_reduce(const uint4* __restrict__ S2q,
                                                  const int2* __restrict__ edge_sw,
                                                  const int2* __restrict__ offs2,
                                                  const float* __restrict__ bias,
                                                  float* __restrict__ out,
                                                  int n_nodes) {
    const int node = blockIdx.x * 4 + (threadIdx.x >> 6);
    if (node >= n_nodes) return;
    const int lane = threadIdx.x & 63;
    const int grp = lane >> 4;    // edge slot within a 4-edge group
    const int ql = lane & 15;     // 16B chunk of the 256B row

    const int2 se = offs2[node];
    const int start = se.x;
    const int end = se.y;

    float acc[8];
#pragma unroll
    for (int j = 0; j < 8; ++j) acc[j] = 0.f;

    for (int base = start; base < end; base += 64) {
        const int cnt = min(64, end - base);
        int2 meta = make_int2(0, 0);  // pad lanes: src=0 (valid row), w=0
        if (lane < cnt) meta = edge_sw[base + lane];

        int i = 0;
        for (; i + 16 <= cnt; i += 16) {
            uint4 gv[4];
            float ws[4];
#pragma unroll
            for (int u = 0; u < 4; ++u) {
                const int idx = i + u * 4 + grp;
                const int s = __shfl(meta.x, idx, 64);
                ws[u] = __int_as_float(__shfl(meta.y, idx, 64));
                gv[u] = S2q[(size_t)s * 16 + ql];
            }
            QEXPAND(gv[0], ws[0]);
            QEXPAND(gv[1], ws[1]);
            QEXPAND(gv[2], ws[2]);
            QEXPAND(gv[3], ws[3]);
        }
        for (; i < cnt; i += 4) {
            const int idx = i + grp;  // idx <= 63; pad slots have w=0
            const int s = __shfl(meta.x, idx, 64);
            const float w = __int_as_float(__shfl(meta.y, idx, 64));
            const uint4 gv = S2q[(size_t)s * 16 + ql];
            QEXPAND(gv, w);
        }
    }

#pragma unroll
    for (int j = 0; j < 8; ++j) {
        acc[j] += __shfl_xor(acc[j], 16, 64);
        acc[j] += __shfl_xor(acc[j], 32, 64);
    }

    if (lane < 16) {
        const float4 b0 = ((const float4*)bias)[ql * 2];
        const float4 b1 = ((const float4*)bias)[ql * 2 + 1];
        float4 o0 = {acc[0] + b0.x, acc[1] + b0.y, acc[2] + b0.z, acc[3] + b0.w};
        float4 o1 = {acc[4] + b1.x, acc[5] + b1.y, acc[6] + b1.z, acc[7] + b1.w};
        float4* orow = (float4*)(out + (size_t)node * DIM) + ql * 2;
        orow[0] = o0;
        orow[1] = o1;
    }
}

extern "C" void kernel_launch(void* const* d_in, const int* in_sizes, int n_in,
                              void* d_out, int out_size, void* d_ws, size_t ws_size,
                              hipStream_t stream) {
    const float* X    = (const float*)d_in[0];
    const float* W    = (const float*)d_in[1];
    const float* bias = (const float*)d_in[2];
    const float* ew   = (const float*)d_in[3];
    const int*   src  = (const int*)d_in[4];
    const int*   dst  = (const int*)d_in[5];
    float* out = (float*)d_out;

    const int n_nodes = in_sizes[0] / DIM;
    const int n_edges = in_sizes[3];

    const int nbkt = (n_nodes + 255) >> 8;                 // 391
    const int nchunks = (n_edges + EPB - 1) / EPB;         // 391

    // Workspace layout (bytes):
    char* ws = (char*)d_ws;
    unsigned short* S2 = (unsigned short*)ws;                         // 25.6 MB
    char* p = ws + (size_t)n_nodes * DIM * 2;
    int* cursor = (int*)p;          p += 512 * 16 * 4;                // 32 KB (padded)
    int2* offs2 = (int2*)p;         p += (size_t)n_nodes * 8;         // 800 KB
    int2* part_sw = (int2*)p;       p += (size_t)nbkt * CAP * 8;      // 15.2 MB
    int2* edge_sw = (int2*)p;                                         // 15.2 MB

    // 1. GEMM (bf16 MFMA) + cursor zeroing
    gemm_xw_mfma<<<(n_nodes + 63) / 64, 256, 0, stream>>>(X, W, S2, cursor, n_nodes);

    // 2. Bump-alloc bucket scatter (per-edge atomics LDS-scope;
    //    391 reservation atomics per block)
    partB_scatter<<<nchunks, 1024, 0, stream>>>(dst, src, ew, cursor, part_sw,
                                                n_edges, nbkt);

    // 3. Per-bucket CSR finish in slotted layout
    partC_csr<<<nbkt, 1024, 0, stream>>>(part_sw, cursor, offs2, edge_sw, n_nodes);

    // 4. Per-node reduction (bias fused, single non-atomic write)
    gcn_reduce<<<(n_nodes + 3) / 4, 256, 0, stream>>>((const uint4*)S2,
                                                      edge_sw, offs2,
                                                      bias, out, n_nodes);
}